// Round 9
// baseline (190.161 us; speedup 1.0000x reference)
//
#include <hip/hip_runtime.h>
#include <math.h>

// Problem dims (fixed by reference)
#define BATCH 32
#define CH    1024     // C == P
#define NPix  784      // H*W = 28*28
#define MMOD  4        // M models, Q == 1
#define NPC   64       // p-chunks (k_nz)
#define PPC   16       // channels per chunk (NPC*PPC == CH)
#define K1B   256      // k_nz block: 4 waves
#define NF4   196      // float4 per 784-pixel row

__device__ __forceinline__ float wave_reduce(float s) {
    #pragma unroll
    for (int off = 32; off; off >>= 1) s += __shfl_down(s, off, 64);
    return s;
}

// Wave64 sum on the VALU pipe (DPP; verified R6/R7). Full sum lands in lane 63.
__device__ __forceinline__ float dpp_wave_sum(float v) {
    int x;
    x = __builtin_amdgcn_update_dpp(0, __builtin_bit_cast(int, v), 0x111, 0xf, 0xf, true);
    v += __builtin_bit_cast(float, x);
    x = __builtin_amdgcn_update_dpp(0, __builtin_bit_cast(int, v), 0x112, 0xf, 0xf, true);
    v += __builtin_bit_cast(float, x);
    x = __builtin_amdgcn_update_dpp(0, __builtin_bit_cast(int, v), 0x114, 0xf, 0xf, true);
    v += __builtin_bit_cast(float, x);
    x = __builtin_amdgcn_update_dpp(0, __builtin_bit_cast(int, v), 0x118, 0xf, 0xf, true);
    v += __builtin_bit_cast(float, x);
    x = __builtin_amdgcn_update_dpp(0, __builtin_bit_cast(int, v), 0x142, 0xa, 0xf, true);
    v += __builtin_bit_cast(float, x);
    x = __builtin_amdgcn_update_dpp(0, __builtin_bit_cast(int, v), 0x143, 0xc, 0xf, true);
    v += __builtin_bit_cast(float, x);
    return v;
}

// R7's k_nz verbatim (best measured). Single-pass norms + z-partials,
// 16 B/lane loads. Block (b,pc) owns 16 channels; thread t<196 holds a
// float4 of each channel (16 independent dwordx4 -> full MLP).
__global__ __launch_bounds__(K1B) void k_nz(const float* __restrict__ x,
                                            const float* __restrict__ Wm,
                                            float* __restrict__ inv_norm,
                                            float* __restrict__ zpart) {
    __shared__ float sq_l[PPC][4];
    __shared__ float4 wl4[PPC];
    const int blk = blockIdx.x;
    const int b  = blk >> 6;         // / NPC
    const int pc = blk & (NPC - 1);
    const int t = threadIdx.x;
    const int wv = t >> 6, lane = t & 63;
    const bool act = (t < NF4);
    const float4* xb4 = (const float4*)(x + ((size_t)b * CH + (size_t)pc * PPC) * NPix);
    const int tt = act ? t : 0;

    float4 xv[PPC];
    #pragma unroll
    for (int pp = 0; pp < PPC; pp++) xv[pp] = xb4[pp * NF4 + tt];  // 16B/lane, coalesced

    #pragma unroll
    for (int pp = 0; pp < PPC; pp++) {
        float4 v = xv[pp];
        float s = act ? (v.x*v.x + v.y*v.y + v.z*v.z + v.w*v.w) : 0.f;
        s = dpp_wave_sum(s);
        if (lane == 63) sq_l[pp][wv] = s;
    }
    __syncthreads();

    if (t < PPC) {
        const float s = sq_l[t][0] + sq_l[t][1] + sq_l[t][2] + sq_l[t][3];
        const float inv = 1.f / fmaxf(sqrtf(s), 1e-10f);
        const int p = pc * PPC + t;
        inv_norm[b * CH + p] = inv;
        float4 w4;
        w4.x = Wm[0 * CH + p] * inv;
        w4.y = Wm[1 * CH + p] * inv;
        w4.z = Wm[2 * CH + p] * inv;
        w4.w = Wm[3 * CH + p] * inv;
        wl4[t] = w4;
    }
    __syncthreads();

    if (act) {
        float4 a0 = {0,0,0,0}, a1 = {0,0,0,0}, a2 = {0,0,0,0}, a3 = {0,0,0,0};
        #pragma unroll
        for (int pp = 0; pp < PPC; pp++) {
            const float4 w = wl4[pp];     // ds_read_b128, same-addr broadcast
            const float4 v = xv[pp];
            a0.x += w.x*v.x; a0.y += w.x*v.y; a0.z += w.x*v.z; a0.w += w.x*v.w;
            a1.x += w.y*v.x; a1.y += w.y*v.y; a1.z += w.y*v.z; a1.w += w.y*v.w;
            a2.x += w.z*v.x; a2.y += w.z*v.y; a2.z += w.z*v.z; a2.w += w.z*v.w;
            a3.x += w.w*v.x; a3.y += w.w*v.y; a3.z += w.w*v.z; a3.w += w.w*v.w;
        }
        float4* zp = (float4*)(zpart + ((size_t)blk * MMOD) * NPix);
        zp[0 * NF4 + t] = a0;
        zp[1 * NF4 + t] = a1;
        zp[2 * NF4 + t] = a2;
        zp[3 * NF4 + t] = a3;
    }
}

// Merged k_gh+k_h (single change vs R7): one block per b, 256 threads,
// t<196 owns 4 pixels (float4). z = sum over 64 fp32 chunks (803KB/block,
// L2/L3); g = sigmoid; s2 per m via DPP + LDS; h = sum_m g/s2.
__global__ __launch_bounds__(256) void k_gh(const float* __restrict__ zpart,
                                            float* __restrict__ h) {
    __shared__ float red[4][MMOD];
    __shared__ float s2s[MMOD];
    const int b = blockIdx.x;
    const int t = threadIdx.x;
    const int wv = t >> 6, lane = t & 63;
    const bool act = t < NF4;
    const int tt = act ? t : 0;

    float4 g4[MMOD];
    #pragma unroll
    for (int m = 0; m < MMOD; m++) {
        float4 z = {0,0,0,0};
        #pragma unroll 8
        for (int pc = 0; pc < NPC; pc++) {
            float4 v = ((const float4*)(zpart + (((size_t)(b * NPC + pc)) * MMOD + m) * NPix))[tt];
            z.x += v.x; z.y += v.y; z.z += v.z; z.w += v.w;
        }
        float4 gg;
        gg.x = 1.f / (1.f + expf(-z.x));
        gg.y = 1.f / (1.f + expf(-z.y));
        gg.z = 1.f / (1.f + expf(-z.z));
        gg.w = 1.f / (1.f + expf(-z.w));
        if (!act) gg = (float4){0,0,0,0};
        g4[m] = gg;
        float s = dpp_wave_sum(gg.x*gg.x + gg.y*gg.y + gg.z*gg.z + gg.w*gg.w);
        if (lane == 63) red[wv][m] = s;
    }
    __syncthreads();
    if (t < MMOD) {
        float s = red[0][t] + red[1][t] + red[2][t] + red[3][t];
        s2s[t] = fmaxf(s, 1e-30f);
    }
    __syncthreads();
    if (act) {
        float4 hv = {0,0,0,0};
        #pragma unroll
        for (int m = 0; m < MMOD; m++) {
            const float r = 1.f / s2s[m];
            hv.x += g4[m].x * r; hv.y += g4[m].y * r;
            hv.z += g4[m].z * r; hv.w += g4[m].w * r;
        }
        ((float4*)(h + (size_t)b * NPix))[t] = hv;
    }
}

// out[b,p] = inv_norm[b,p] * dot(x[b,p,:], h[b,:]). One wave per row,
// float4 throughout (R4/R7-validated, near L3-stream-bound).
__global__ __launch_bounds__(256) void k_out(const float* __restrict__ x,
                                             const float* __restrict__ h,
                                             const float* __restrict__ inv_norm,
                                             float* __restrict__ out) {
    const int r = blockIdx.x * 4 + (threadIdx.x >> 6);  // r in [0, 32768)
    const int lane = threadIdx.x & 63;
    const int b = r >> 10;
    const float4* x4 = (const float4*)(x + (size_t)r * NPix);
    const float4* h4 = (const float4*)(h + (size_t)b * NPix);
    float s = 0.f;
    #pragma unroll
    for (int i = 0; i < 3; i++) {
        float4 xv = x4[i * 64 + lane];
        float4 hv = h4[i * 64 + lane];
        s += xv.x*hv.x + xv.y*hv.y + xv.z*hv.z + xv.w*hv.w;
    }
    if (lane < 4) {
        float4 xv = x4[192 + lane];
        float4 hv = h4[192 + lane];
        s += xv.x*hv.x + xv.y*hv.y + xv.z*hv.z + xv.w*hv.w;
    }
    s = wave_reduce(s);
    if (lane == 0) {
        float v = s * inv_norm[r];
        // nan_to_num semantics: nan->0, +/-inf -> +/-FLT_MAX
        if (!(v == v)) v = 0.f;
        v = fminf(fmaxf(v, -3.402823466e+38f), 3.402823466e+38f);
        out[r] = v;
    }
}

extern "C" void kernel_launch(void* const* d_in, const int* in_sizes, int n_in,
                              void* d_out, int out_size, void* d_ws, size_t ws_size,
                              hipStream_t stream) {
    const float* x  = (const float*)d_in[0];   // [32,1024,28,28]
    const float* Wm = (const float*)d_in[1];   // [4,1,1024]
    float* out = (float*)d_out;                // [32,1024]
    float* wsf = (float*)d_ws;

    float* inv_norm = wsf;                                        // 32768 floats
    float* h        = inv_norm + BATCH * CH;                      // 25088 floats
    float* zpart    = h + BATCH * NPix;                           // 32*64*4*784 = 6422528 floats

    k_nz<<<BATCH * NPC, K1B, 0, stream>>>(x, Wm, inv_norm, zpart);
    k_gh<<<BATCH, 256, 0, stream>>>(zpart, h);
    k_out<<<BATCH * CH / 4, 256, 0, stream>>>(x, h, inv_norm, out);
}

// Round 10
// 177.263 us; speedup vs baseline: 1.0728x; 1.0728x over previous
//
#include <hip/hip_runtime.h>
#include <math.h>

// Problem dims (fixed by reference)
#define BATCH 32
#define CH    1024     // C == P
#define NPix  784      // H*W = 28*28
#define MMOD  4        // M models, Q == 1
#define NPC   64       // p-chunks (k_nz)
#define PPC   16       // channels per chunk (NPC*PPC == CH)
#define K1B   256      // k_nz block: 4 waves
#define NF4   196      // float4 per 784-pixel row

__device__ __forceinline__ float wave_reduce(float s) {
    #pragma unroll
    for (int off = 32; off; off >>= 1) s += __shfl_down(s, off, 64);
    return s;
}

// Wave64 sum on the VALU pipe (DPP; verified R6/R7). Full sum lands in lane 63.
__device__ __forceinline__ float dpp_wave_sum(float v) {
    int x;
    x = __builtin_amdgcn_update_dpp(0, __builtin_bit_cast(int, v), 0x111, 0xf, 0xf, true);
    v += __builtin_bit_cast(float, x);
    x = __builtin_amdgcn_update_dpp(0, __builtin_bit_cast(int, v), 0x112, 0xf, 0xf, true);
    v += __builtin_bit_cast(float, x);
    x = __builtin_amdgcn_update_dpp(0, __builtin_bit_cast(int, v), 0x114, 0xf, 0xf, true);
    v += __builtin_bit_cast(float, x);
    x = __builtin_amdgcn_update_dpp(0, __builtin_bit_cast(int, v), 0x118, 0xf, 0xf, true);
    v += __builtin_bit_cast(float, x);
    x = __builtin_amdgcn_update_dpp(0, __builtin_bit_cast(int, v), 0x142, 0xa, 0xf, true);
    v += __builtin_bit_cast(float, x);
    x = __builtin_amdgcn_update_dpp(0, __builtin_bit_cast(int, v), 0x143, 0xc, 0xf, true);
    v += __builtin_bit_cast(float, x);
    return v;
}

// R7's k_nz verbatim (best measured across R3/R6/R8/R9 alternatives).
// Single-pass norms + z-partials, 16 B/lane loads. Block (b,pc) owns 16
// channels; thread t<196 holds a float4 of each (16 independent dwordx4).
__global__ __launch_bounds__(K1B) void k_nz(const float* __restrict__ x,
                                            const float* __restrict__ Wm,
                                            float* __restrict__ inv_norm,
                                            float* __restrict__ zpart) {
    __shared__ float sq_l[PPC][4];
    __shared__ float4 wl4[PPC];
    const int blk = blockIdx.x;
    const int b  = blk >> 6;         // / NPC
    const int pc = blk & (NPC - 1);
    const int t = threadIdx.x;
    const int wv = t >> 6, lane = t & 63;
    const bool act = (t < NF4);
    const float4* xb4 = (const float4*)(x + ((size_t)b * CH + (size_t)pc * PPC) * NPix);
    const int tt = act ? t : 0;

    float4 xv[PPC];
    #pragma unroll
    for (int pp = 0; pp < PPC; pp++) xv[pp] = xb4[pp * NF4 + tt];  // 16B/lane, coalesced

    #pragma unroll
    for (int pp = 0; pp < PPC; pp++) {
        float4 v = xv[pp];
        float s = act ? (v.x*v.x + v.y*v.y + v.z*v.z + v.w*v.w) : 0.f;
        s = dpp_wave_sum(s);
        if (lane == 63) sq_l[pp][wv] = s;
    }
    __syncthreads();

    if (t < PPC) {
        const float s = sq_l[t][0] + sq_l[t][1] + sq_l[t][2] + sq_l[t][3];
        const float inv = 1.f / fmaxf(sqrtf(s), 1e-10f);
        const int p = pc * PPC + t;
        inv_norm[b * CH + p] = inv;
        float4 w4;
        w4.x = Wm[0 * CH + p] * inv;
        w4.y = Wm[1 * CH + p] * inv;
        w4.z = Wm[2 * CH + p] * inv;
        w4.w = Wm[3 * CH + p] * inv;
        wl4[t] = w4;
    }
    __syncthreads();

    if (act) {
        float4 a0 = {0,0,0,0}, a1 = {0,0,0,0}, a2 = {0,0,0,0}, a3 = {0,0,0,0};
        #pragma unroll
        for (int pp = 0; pp < PPC; pp++) {
            const float4 w = wl4[pp];     // ds_read_b128, same-addr broadcast
            const float4 v = xv[pp];
            a0.x += w.x*v.x; a0.y += w.x*v.y; a0.z += w.x*v.z; a0.w += w.x*v.w;
            a1.x += w.y*v.x; a1.y += w.y*v.y; a1.z += w.y*v.z; a1.w += w.y*v.w;
            a2.x += w.z*v.x; a2.y += w.z*v.y; a2.z += w.z*v.z; a2.w += w.z*v.w;
            a3.x += w.w*v.x; a3.y += w.w*v.y; a3.z += w.w*v.z; a3.w += w.w*v.w;
        }
        float4* zp = (float4*)(zpart + ((size_t)blk * MMOD) * NPix);
        zp[0 * NF4 + t] = a0;
        zp[1 * NF4 + t] = a1;
        zp[2 * NF4 + t] = a2;
        zp[3 * NF4 + t] = a3;
    }
}

// Per (b,m) block (grid 128 — R9 lesson: never shrink the grid for fusion).
// ONE change vs R7: float4 zpart reads (64 dwordx4/thread) instead of scalar
// dwords — same VMEM-issue fix that won R6->R7 on k_nz.
__global__ __launch_bounds__(256) void k_gh(const float* __restrict__ zpart,
                                            float* __restrict__ g_out,
                                            float* __restrict__ s2g) {
    __shared__ float red[4];
    const int blk = blockIdx.x;
    const int b = blk >> 2;
    const int m = blk & 3;
    const int t = threadIdx.x;
    const int wv = t >> 6, lane = t & 63;
    const bool act = t < NF4;
    const int tt = act ? t : 0;
    const float4* zp4 = (const float4*)zpart;

    float4 z = {0,0,0,0};
    #pragma unroll 8
    for (int pc = 0; pc < NPC; pc++) {
        float4 v = zp4[((size_t)(b * NPC + pc) * MMOD + m) * NF4 + tt];
        z.x += v.x; z.y += v.y; z.z += v.z; z.w += v.w;
    }
    float4 g;
    g.x = 1.f / (1.f + expf(-z.x));
    g.y = 1.f / (1.f + expf(-z.y));
    g.z = 1.f / (1.f + expf(-z.z));
    g.w = 1.f / (1.f + expf(-z.w));
    if (!act) g = (float4){0,0,0,0};

    float s = dpp_wave_sum(g.x*g.x + g.y*g.y + g.z*g.z + g.w*g.w);
    if (lane == 63) red[wv] = s;
    __syncthreads();
    if (t == 0) s2g[blk] = fmaxf(red[0] + red[1] + red[2] + red[3], 1e-30f);
    if (act) ((float4*)(g_out + (size_t)blk * NPix))[t] = g;
}

// h[b,n] = sum_m g[b,m,n] / s2[b,m]. Tiny (32 blocks); float4 reads/writes.
__global__ __launch_bounds__(256) void k_h(const float* __restrict__ g_out,
                                           const float* __restrict__ s2g,
                                           float* __restrict__ h) {
    const int b = blockIdx.x;
    const int t = threadIdx.x;
    if (t < NF4) {
        float4 hv = {0,0,0,0};
        #pragma unroll
        for (int m = 0; m < MMOD; m++) {
            const float4 g = ((const float4*)(g_out + (size_t)(b * MMOD + m) * NPix))[t];
            const float r = 1.f / s2g[b * MMOD + m];
            hv.x += g.x * r; hv.y += g.y * r; hv.z += g.z * r; hv.w += g.w * r;
        }
        ((float4*)(h + (size_t)b * NPix))[t] = hv;
    }
}

// out[b,p] = inv_norm[b,p] * dot(x[b,p,:], h[b,:]). One wave per row,
// float4 throughout (R4/R7-validated, near L3-stream-bound).
__global__ __launch_bounds__(256) void k_out(const float* __restrict__ x,
                                             const float* __restrict__ h,
                                             const float* __restrict__ inv_norm,
                                             float* __restrict__ out) {
    const int r = blockIdx.x * 4 + (threadIdx.x >> 6);  // r in [0, 32768)
    const int lane = threadIdx.x & 63;
    const int b = r >> 10;
    const float4* x4 = (const float4*)(x + (size_t)r * NPix);
    const float4* h4 = (const float4*)(h + (size_t)b * NPix);
    float s = 0.f;
    #pragma unroll
    for (int i = 0; i < 3; i++) {
        float4 xv = x4[i * 64 + lane];
        float4 hv = h4[i * 64 + lane];
        s += xv.x*hv.x + xv.y*hv.y + xv.z*hv.z + xv.w*hv.w;
    }
    if (lane < 4) {
        float4 xv = x4[192 + lane];
        float4 hv = h4[192 + lane];
        s += xv.x*hv.x + xv.y*hv.y + xv.z*hv.z + xv.w*hv.w;
    }
    s = wave_reduce(s);
    if (lane == 0) {
        float v = s * inv_norm[r];
        // nan_to_num semantics: nan->0, +/-inf -> +/-FLT_MAX
        if (!(v == v)) v = 0.f;
        v = fminf(fmaxf(v, -3.402823466e+38f), 3.402823466e+38f);
        out[r] = v;
    }
}

extern "C" void kernel_launch(void* const* d_in, const int* in_sizes, int n_in,
                              void* d_out, int out_size, void* d_ws, size_t ws_size,
                              hipStream_t stream) {
    const float* x  = (const float*)d_in[0];   // [32,1024,28,28]
    const float* Wm = (const float*)d_in[1];   // [4,1,1024]
    float* out = (float*)d_out;                // [32,1024]
    float* wsf = (float*)d_ws;

    float* inv_norm = wsf;                                        // 32768 floats
    float* zpart    = inv_norm + BATCH * CH;                      // 32*64*4*784 = 6422528 floats
    float* g_out    = zpart + (size_t)BATCH * NPC * MMOD * NPix;  // 32*4*784 floats
    float* s2g      = g_out + (size_t)BATCH * MMOD * NPix;        // 128 floats
    float* h        = s2g + BATCH * MMOD;                         // 25088 floats

    k_nz<<<BATCH * NPC, K1B, 0, stream>>>(x, Wm, inv_norm, zpart);
    k_gh<<<BATCH * MMOD, 256, 0, stream>>>(zpart, g_out, s2g);
    k_h<<<BATCH, 256, 0, stream>>>(g_out, s2g, h);
    k_out<<<BATCH * CH / 4, 256, 0, stream>>>(x, h, inv_norm, out);
}